// Round 3
// baseline (230.318 us; speedup 1.0000x reference)
//
#include <hip/hip_runtime.h>
#include <math.h>

#define B_  2
#define S_  2048
#define D_  1024
#define H_  16
#define DH_ 64

typedef unsigned short u16;
typedef unsigned int   u32;
typedef _Float16       f16;
typedef _Float16 half8  __attribute__((ext_vector_type(8)));
typedef _Float16 half4  __attribute__((ext_vector_type(4)));
typedef float    f32x4  __attribute__((ext_vector_type(4)));

#if __has_builtin(__builtin_amdgcn_exp2f)
#define EXP2(x) __builtin_amdgcn_exp2f(x)
#else
#define EXP2(x) exp2f(x)
#endif

__device__ __forceinline__ u16 h_bits(f16 h){ return __builtin_bit_cast(u16, h); }

// ---------------------------------------------------------------------------
// Kernel 1: prep = split_x + convert_w fused (UNCHANGED).
// ---------------------------------------------------------------------------
__global__ __launch_bounds__(256) void prep_kernel(
    const float* __restrict__ X,
    const float* __restrict__ Wq, const float* __restrict__ Wk,
    const float* __restrict__ Wv,
    u16* __restrict__ Xhi, u16* __restrict__ Xlo, u16* __restrict__ Wt)
{
    __shared__ float Wf[64][65];
    const int bid = blockIdx.x;
    const int c   = threadIdx.x;

    if (bid < 4096){
        const int idx = bid * 256 + c;
        float4 v = ((const float4*)X)[idx];
        float fv[4] = {v.x, v.y, v.z, v.w};
        u16 hh[4], ll[4];
        #pragma unroll
        for (int j = 0; j < 4; ++j){
            f16 hi = (f16)fv[j];
            hh[j] = h_bits(hi);
            ll[j] = h_bits((f16)(fv[j] - (float)hi));
        }
        uint2 ph, pl;
        ph.x = hh[0] | ((u32)hh[1] << 16);
        ph.y = hh[2] | ((u32)hh[3] << 16);
        pl.x = ll[0] | ((u32)ll[1] << 16);
        pl.y = ll[2] | ((u32)ll[3] << 16);
        ((uint2*)Xhi)[idx] = ph;
        ((uint2*)Xlo)[idx] = pl;
        return;
    }

    const int wb = bid - 4096;          // 0..767
    const int d0 = (wb & 15) * 64;
    const int h  = (wb >> 4) & 15;
    const int which = wb >> 8;
    const float* src = (which == 0) ? Wq : (which == 1) ? Wk : Wv;
    src += (size_t)h * D_ * DH_;

    #pragma unroll
    for (int it = 0; it < 4; ++it){
        int d  = (c >> 4) + 16 * it;
        int e4 = (c & 15) * 4;
        float4 v = *(const float4*)(src + (size_t)(d0 + d) * DH_ + e4);
        Wf[d][e4+0] = v.x; Wf[d][e4+1] = v.y; Wf[d][e4+2] = v.z; Wf[d][e4+3] = v.w;
    }
    __syncthreads();
    u16* dst = Wt + (size_t)(which * H_ + h) * DH_ * D_;
    #pragma unroll
    for (int it = 0; it < 4; ++it){
        int e  = (c >> 4) + 16 * it;
        int d4 = (c & 15) * 4;
        u16 q[4];
        #pragma unroll
        for (int j = 0; j < 4; ++j)
            q[j] = h_bits((f16)(Wf[d4 + j][e] * 64.0f));
        u32* p = (u32*)(dst + (size_t)e * D_ + d0 + d4);
        p[0] = q[0] | ((u32)q[1] << 16);
        p[1] = q[2] | ((u32)q[3] << 16);
    }
}

// ---------------------------------------------------------------------------
// Kernel 2: proj — REVERTED to the R0 structure (proven 64.4 us twice; both
// 8-phase ports measured slower: 76.1, 68.2).  128x128 tiles, 4 waves, BK=32,
// PKS=40 LDS stride (conflict profile known), register prefetch, 3 blocks/CU.
// ---------------------------------------------------------------------------
#define PKS 40

__global__ __launch_bounds__(256, 3) void proj_kernel(
    const u16* __restrict__ Xhi, const u16* __restrict__ Xlo,
    const u16* __restrict__ Wt,
    const float* __restrict__ bq, const float* __restrict__ bk,
    const float* __restrict__ bv,
    f16* __restrict__ Qh, f16* __restrict__ Kh, f16* __restrict__ Vt)
{
    __shared__ u16 XsHi[128 * PKS], XsLo[128 * PKS], Bs[128 * PKS];

    const int tid  = threadIdx.x;
    const int lane = tid & 63;
    const int w    = tid >> 6;
    const int quad = lane >> 4;
    const int ln   = lane & 15;
    const int wr   = (w >> 1) * 64;
    const int wc   = (w & 1) * 64;
    const int m0   = blockIdx.x * 128;
    const int c0   = blockIdx.y * 128;

    const int sr  = tid >> 2;          // 0..63
    const int sch = (tid & 3) * 8;     // 0,8,16,24

    const u16* xh0 = Xhi + (size_t)(m0 + sr) * D_ + sch;
    const u16* xh1 = xh0 + (size_t)64 * D_;
    const u16* xl0 = Xlo + (size_t)(m0 + sr) * D_ + sch;
    const u16* xl1 = xl0 + (size_t)64 * D_;
    const u16* wb0 = Wt  + (size_t)(c0 + sr) * D_ + sch;
    const u16* wb1 = wb0 + (size_t)64 * D_;

    uint4 rh0 = *(const uint4*)xh0, rh1 = *(const uint4*)xh1;
    uint4 rl0 = *(const uint4*)xl0, rl1 = *(const uint4*)xl1;
    uint4 rw0 = *(const uint4*)wb0, rw1 = *(const uint4*)wb1;

    f32x4 acc[4][4];
    #pragma unroll
    for (int i = 0; i < 4; ++i)
        #pragma unroll
        for (int j = 0; j < 4; ++j)
            acc[i][j] = (f32x4){0.f, 0.f, 0.f, 0.f};

    for (int k0 = 0; k0 < D_; k0 += 32){
        __syncthreads();
        *(uint4*)&XsHi[sr * PKS + sch]        = rh0;
        *(uint4*)&XsHi[(sr + 64) * PKS + sch] = rh1;
        *(uint4*)&XsLo[sr * PKS + sch]        = rl0;
        *(uint4*)&XsLo[(sr + 64) * PKS + sch] = rl1;
        *(uint4*)&Bs[sr * PKS + sch]          = rw0;
        *(uint4*)&Bs[(sr + 64) * PKS + sch]   = rw1;
        const int kn = k0 + 32;
        if (kn < D_){
            rh0 = *(const uint4*)(xh0 + kn); rh1 = *(const uint4*)(xh1 + kn);
            rl0 = *(const uint4*)(xl0 + kn); rl1 = *(const uint4*)(xl1 + kn);
            rw0 = *(const uint4*)(wb0 + kn); rw1 = *(const uint4*)(wb1 + kn);
        }
        __syncthreads();

        half8 ahi[4], alo[4], bf[4];
        #pragma unroll
        for (int mt = 0; mt < 4; ++mt){
            int row = wr + 16 * mt + ln;
            ahi[mt] = __builtin_bit_cast(half8, *(const uint4*)&XsHi[row * PKS + quad * 8]);
            alo[mt] = __builtin_bit_cast(half8, *(const uint4*)&XsLo[row * PKS + quad * 8]);
        }
        #pragma unroll
        for (int nt = 0; nt < 4; ++nt)
            bf[nt] = __builtin_bit_cast(half8,
                *(const uint4*)&Bs[(wc + 16 * nt + ln) * PKS + quad * 8]);
        #pragma unroll
        for (int mt = 0; mt < 4; ++mt)
            #pragma unroll
            for (int nt = 0; nt < 4; ++nt){
                acc[mt][nt] = __builtin_amdgcn_mfma_f32_16x16x32_f16(ahi[mt], bf[nt], acc[mt][nt], 0, 0, 0);
                acc[mt][nt] = __builtin_amdgcn_mfma_f32_16x16x32_f16(alo[mt], bf[nt], acc[mt][nt], 0, 0, 0);
            }
    }

    const float QSCALE = 0.125f * 1.44269504088896340736f;
    const float INV64  = 0.015625f;
    #pragma unroll
    for (int nt = 0; nt < 4; ++nt){
        int colg  = c0 + wc + 16 * nt + ln;
        int which = colg >> 10;          // uniform within the 16-col group
        int h     = (colg >> 6) & 15;    // uniform within the 16-col group
        int e     = colg & 63;
        const float* bp = (which == 0) ? bq : (which == 1) ? bk : bv;
        float bias = bp[h * DH_ + e];
        if (which < 2){
            f16* op = (which == 0) ? Qh : Kh;
            float scale = (which == 0) ? QSCALE : 1.0f;
            #pragma unroll
            for (int mt = 0; mt < 4; ++mt)
                #pragma unroll
                for (int r = 0; r < 4; ++r){
                    int sg = m0 + wr + 16 * mt + 4 * quad + r;
                    int b  = sg >> 11;
                    int s  = sg & (S_ - 1);
                    float val = (acc[mt][nt][r] * INV64 + bias) * scale;
                    op[((size_t)(b * H_ + h) * S_ + s) * DH_ + e] = (f16)val;
                }
        } else {
            // V: write transposed Vt[bh][e][t]; 4 consecutive s -> 8B store
            #pragma unroll
            for (int mt = 0; mt < 4; ++mt){
                int sg0 = m0 + wr + 16 * mt + 4 * quad;
                int b   = sg0 >> 11;
                int s0  = sg0 & (S_ - 1);
                u16 p[4];
                #pragma unroll
                for (int r = 0; r < 4; ++r)
                    p[r] = h_bits((f16)(acc[mt][nt][r] * INV64 + bias));
                uint2 pk;
                pk.x = p[0] | ((u32)p[1] << 16);
                pk.y = p[2] | ((u32)p[3] << 16);
                *(uint2*)((u16*)Vt + ((size_t)((b * H_ + h) * DH_ + e)) * S_ + s0) = pk;
            }
        }
    }
}

// ---------------------------------------------------------------------------
// Kernel 3 (R3): attention with 32 q-rows per wave (two 16-col Q groups
// sharing every K/V LDS read).  Same loop skeleton as the proven R0 kernel,
// but each kf/vf ds_read now feeds TWO MFMAs -> LDS traffic and barrier
// count per FLOP halve; per-wave ILP doubles (2 independent acc streams).
// Per-q math is bit-identical to R0 (same per-tile summation order).
// Diagonal-only masking preserved: both group bases (qbase, qbase+16) are
// multiples of 16 -> exactly one partial subtile per group.
// grid (32 hb, 16 pairs), block 256 (4 waves), LDS 18.4 KB; ~130 VGPR
// -> launch_bounds(256,2).  XCD mapping unchanged (blockIdx.x = hb).
// ---------------------------------------------------------------------------
#define AKS 72

__global__ __launch_bounds__(256, 2) void attn_kernel(
    const f16* __restrict__ Qh, const f16* __restrict__ Kh,
    const f16* __restrict__ Vt, float* __restrict__ Out)
{
    __shared__ u16 Ks[64 * AKS];   // K tile [t][e]
    __shared__ u16 Vs[64 * AKS];   // V tile [e][t]

    const int tid  = threadIdx.x;
    const int lane = tid & 63;
    const int w    = tid >> 6;
    const int quad = lane >> 4;
    const int ln   = lane & 15;
    const int hb   = blockIdx.x;            // b*H + h  (XCD = hb % 8)
    const int i    = blockIdx.y;            // pair index 0..15
    const int h    = hb & 15;
    const int b    = hb >> 4;
    const int bh   = hb;
    const int sub  = w & 1;
    // wave covers 32 q-rows: [qbase, qbase+32)
    const int qbase = (w >> 1) ? (S_ - 64 * (i + 1) + 32 * sub)
                               : (64 * i + 32 * sub);
    const int vmax  = S_ - 64 * i - 1;      // highest t any wave's PV needs

    const u16* Qg = (const u16*)Qh + (size_t)bh * S_ * DH_;
    const u16* Kg = (const u16*)Kh + (size_t)bh * S_ * DH_;
    const u16* Vg = (const u16*)Vt + (size_t)bh * DH_ * S_;

    // Q fragments for both 16-col groups (B-operand: n=q=ln, k=32ks+8quad+j)
    half8 qf0[2], qf1[2];
    #pragma unroll
    for (int ks = 0; ks < 2; ++ks){
        qf0[ks] = __builtin_bit_cast(half8,
            *(const uint4*)(Qg + (size_t)(qbase + ln) * DH_ + 32 * ks + 8 * quad));
        qf1[ks] = __builtin_bit_cast(half8,
            *(const uint4*)(Qg + (size_t)(qbase + 16 + ln) * DH_ + 32 * ks + 8 * quad));
    }

    // staging coords: thread covers K rows kr,kr+32 / V rows (e) kr,kr+32
    const int kr = tid >> 3;
    const int kc = (tid & 7) * 8;

    // prefetch tile 0 into registers
    uint4 kA = *(const uint4*)(Kg + (size_t)kr * DH_ + kc);
    uint4 kB = *(const uint4*)(Kg + (size_t)(kr + 32) * DH_ + kc);
    uint4 vA = *(const uint4*)(Vg + (size_t)kr * S_ + kc);
    uint4 vB = *(const uint4*)(Vg + (size_t)(kr + 32) * S_ + kc);

    float l0 = 0.f, l1 = 0.f;
    f32x4 oa0[4], oa1[4];
    #pragma unroll
    for (int nt = 0; nt < 4; ++nt){
        oa0[nt] = (f32x4){0.f, 0.f, 0.f, 0.f};
        oa1[nt] = (f32x4){0.f, 0.f, 0.f, 0.f};
    }

    const int qrow0 = qbase + ln;        // group0 lane q
    const int qrow1 = qbase + 16 + ln;   // group1 lane q
    const int pvl0  = qbase + 15;        // wave-uniform PV bounds
    const int pvl1  = qbase + 31;

    for (int t0 = 0; t0 < S_; t0 += 64){
        __syncthreads();               // all waves done reading prev tile
        *(uint4*)&Ks[kr * AKS + kc]        = kA;
        *(uint4*)&Ks[(kr + 32) * AKS + kc] = kB;
        if (t0 <= vmax){
            *(uint4*)&Vs[kr * AKS + kc]        = vA;
            *(uint4*)&Vs[(kr + 32) * AKS + kc] = vB;
        }
        // prefetch tile t0+64 (hidden behind this tile's compute)
        const int tn = t0 + 64;
        if (tn < S_){
            kA = *(const uint4*)(Kg + (size_t)(tn + kr) * DH_ + kc);
            kB = *(const uint4*)(Kg + (size_t)(tn + kr + 32) * DH_ + kc);
            if (tn <= vmax){
                vA = *(const uint4*)(Vg + (size_t)kr * S_ + tn + kc);
                vB = *(const uint4*)(Vg + (size_t)(kr + 32) * S_ + tn + kc);
            }
        }
        __syncthreads();               // LDS tile ready

        // S^T tile: A = K frags (m=t), B = Q frags (n=q); each kf feeds both
        // q groups -> 8 ds_reads, 16 MFMAs.
        f32x4 s0[4], s1[4];
        #pragma unroll
        for (int mt = 0; mt < 4; ++mt){
            s0[mt] = (f32x4){0.f, 0.f, 0.f, 0.f};
            s1[mt] = (f32x4){0.f, 0.f, 0.f, 0.f};
        }
        #pragma unroll
        for (int ks = 0; ks < 2; ++ks)
            #pragma unroll
            for (int mt = 0; mt < 4; ++mt){
                half8 kf = __builtin_bit_cast(half8,
                    *(const uint4*)&Ks[(16 * mt + ln) * AKS + 32 * ks + 8 * quad]);
                s0[mt] = __builtin_amdgcn_mfma_f32_16x16x32_f16(kf, qf0[ks], s0[mt], 0, 0, 0);
                s1[mt] = __builtin_amdgcn_mfma_f32_16x16x32_f16(kf, qf1[ks], s1[mt], 0, 0, 0);
            }

        // p = exp2(s); denominators = plain running row-sums over ALL t
        #pragma unroll
        for (int mt = 0; mt < 4; ++mt)
            #pragma unroll
            for (int r = 0; r < 4; ++r){
                s0[mt][r] = EXP2(s0[mt][r]);
                s1[mt][r] = EXP2(s1[mt][r]);
            }
        {
            float sa = ((s0[0][0] + s0[0][1] + s0[0][2] + s0[0][3]) +
                        (s0[1][0] + s0[1][1] + s0[1][2] + s0[1][3])) +
                       ((s0[2][0] + s0[2][1] + s0[2][2] + s0[2][3]) +
                        (s0[3][0] + s0[3][1] + s0[3][2] + s0[3][3]));
            sa += __shfl_xor(sa, 16);
            sa += __shfl_xor(sa, 32);
            l0 += sa;
            float sb = ((s1[0][0] + s1[0][1] + s1[0][2] + s1[0][3]) +
                        (s1[1][0] + s1[1][1] + s1[1][2] + s1[1][3])) +
                       ((s1[2][0] + s1[2][1] + s1[2][2] + s1[2][3]) +
                        (s1[3][0] + s1[3][1] + s1[3][2] + s1[3][3]));
            sb += __shfl_xor(sb, 16);
            sb += __shfl_xor(sb, 32);
            l1 += sb;
        }

        // PV per 16-t subtile; per group exactly one partial subtile.
        #pragma unroll
        for (int mt = 0; mt < 4; ++mt){
            const int ts = t0 + 16 * mt;
            if (ts <= pvl1){           // wave-uniform: at least group1 active
                const int g0on = (ts <= pvl0);   // wave-uniform
                half4 pf1;
                if (ts == qbase + 16){ // group1's one partial subtile
                    int tb = ts + 4 * quad;
                    #pragma unroll
                    for (int r = 0; r < 4; ++r)
                        pf1[r] = (tb + r > qrow1) ? (f16)0.f : (f16)s1[mt][r];
                } else {
                    #pragma unroll
                    for (int r = 0; r < 4; ++r)
                        pf1[r] = (f16)s1[mt][r];
                }
                half4 pf0;
                if (g0on){
                    if (ts == qbase){  // group0's one partial subtile
                        int tb = ts + 4 * quad;
                        #pragma unroll
                        for (int r = 0; r < 4; ++r)
                            pf0[r] = (tb + r > qrow0) ? (f16)0.f : (f16)s0[mt][r];
                    } else {
                        #pragma unroll
                        for (int r = 0; r < 4; ++r)
                            pf0[r] = (f16)s0[mt][r];
                    }
                }
                #pragma unroll
                for (int nt = 0; nt < 4; ++nt){
                    half4 vf = __builtin_bit_cast(half4,
                        *(const uint2*)&Vs[(16 * nt + ln) * AKS + 16 * mt + 4 * quad]);
                    oa1[nt] = __builtin_amdgcn_mfma_f32_16x16x16f16(pf1, vf, oa1[nt], 0, 0, 0);
                    if (g0on)
                        oa0[nt] = __builtin_amdgcn_mfma_f32_16x16x16f16(pf0, vf, oa0[nt], 0, 0, 0);
                }
            }
        }
    }

    // epilogue: group g rows at q = qbase+16g+4quad+r; l lives at lane ln=row
    #pragma unroll
    for (int r = 0; r < 4; ++r){
        float lv0  = __shfl(l0, (lane & 48) | (4 * quad + r));
        float inv0 = 1.0f / lv0;
        int sg0 = qbase + 4 * quad + r;
        float* op0 = Out + ((size_t)b * S_ + sg0) * D_ + h * DH_;
        #pragma unroll
        for (int nt = 0; nt < 4; ++nt)
            op0[16 * nt + ln] = oa0[nt][r] * inv0;

        float lv1  = __shfl(l1, (lane & 48) | (4 * quad + r));
        float inv1 = 1.0f / lv1;
        int sg1 = qbase + 16 + 4 * quad + r;
        float* op1 = Out + ((size_t)b * S_ + sg1) * D_ + h * DH_;
        #pragma unroll
        for (int nt = 0; nt < 4; ++nt)
            op1[16 * nt + ln] = oa1[nt][r] * inv1;
    }
}

// ---------------------------------------------------------------------------
extern "C" void kernel_launch(void* const* d_in, const int* in_sizes, int n_in,
                              void* d_out, int out_size, void* d_ws, size_t ws_size,
                              hipStream_t stream)
{
    const float* X  = (const float*)d_in[0];
    const float* Wq = (const float*)d_in[1];
    const float* bq = (const float*)d_in[2];
    const float* Wk = (const float*)d_in[3];
    const float* bk = (const float*)d_in[4];
    const float* Wv = (const float*)d_in[5];
    const float* bv = (const float*)d_in[6];
    float* out = (float*)d_out;

    // workspace (46 MiB): Wt | Qh | Kh | Vt | Xhi | Xlo  (unchanged layout)
    u16* Wt  = (u16*)d_ws;                    // 3,145,728 u16
    f16* Qh  = (f16*)(Wt + 3145728);
    f16* Kh  = Qh + 4194304;
    f16* Vt  = Kh + 4194304;
    u16* Xhi = (u16*)(Vt + 4194304);
    u16* Xlo = Xhi + 4194304;

    prep_kernel<<<dim3(4096 + 768), 256, 0, stream>>>(X, Wq, Wk, Wv, Xhi, Xlo, Wt);
    proj_kernel<<<dim3(32, 24), 256, 0, stream>>>(Xhi, Xlo, Wt, bq, bk, bv, Qh, Kh, Vt);
    attn_kernel<<<dim3(32, 16), 256, 0, stream>>>(Qh, Kh, Vt, out);
}

// Round 4
// 195.199 us; speedup vs baseline: 1.1799x; 1.1799x over previous
//
#include <hip/hip_runtime.h>
#include <math.h>

#define B_  2
#define S_  2048
#define D_  1024
#define H_  16
#define DH_ 64

typedef unsigned short u16;
typedef unsigned int   u32;
typedef _Float16       f16;
typedef _Float16 half8  __attribute__((ext_vector_type(8)));
typedef _Float16 half4  __attribute__((ext_vector_type(4)));
typedef float    f32x4  __attribute__((ext_vector_type(4)));

#if __has_builtin(__builtin_amdgcn_exp2f)
#define EXP2(x) __builtin_amdgcn_exp2f(x)
#else
#define EXP2(x) exp2f(x)
#endif

__device__ __forceinline__ u16 h_bits(f16 h){ return __builtin_bit_cast(u16, h); }

// ---------------------------------------------------------------------------
// Kernel 1: prep = split_x + convert_w fused (UNCHANGED, proven).
// ---------------------------------------------------------------------------
__global__ __launch_bounds__(256) void prep_kernel(
    const float* __restrict__ X,
    const float* __restrict__ Wq, const float* __restrict__ Wk,
    const float* __restrict__ Wv,
    u16* __restrict__ Xhi, u16* __restrict__ Xlo, u16* __restrict__ Wt)
{
    __shared__ float Wf[64][65];
    const int bid = blockIdx.x;
    const int c   = threadIdx.x;

    if (bid < 4096){
        const int idx = bid * 256 + c;
        float4 v = ((const float4*)X)[idx];
        float fv[4] = {v.x, v.y, v.z, v.w};
        u16 hh[4], ll[4];
        #pragma unroll
        for (int j = 0; j < 4; ++j){
            f16 hi = (f16)fv[j];
            hh[j] = h_bits(hi);
            ll[j] = h_bits((f16)(fv[j] - (float)hi));
        }
        uint2 ph, pl;
        ph.x = hh[0] | ((u32)hh[1] << 16);
        ph.y = hh[2] | ((u32)hh[3] << 16);
        pl.x = ll[0] | ((u32)ll[1] << 16);
        pl.y = ll[2] | ((u32)ll[3] << 16);
        ((uint2*)Xhi)[idx] = ph;
        ((uint2*)Xlo)[idx] = pl;
        return;
    }

    const int wb = bid - 4096;          // 0..767
    const int d0 = (wb & 15) * 64;
    const int h  = (wb >> 4) & 15;
    const int which = wb >> 8;
    const float* src = (which == 0) ? Wq : (which == 1) ? Wk : Wv;
    src += (size_t)h * D_ * DH_;

    #pragma unroll
    for (int it = 0; it < 4; ++it){
        int d  = (c >> 4) + 16 * it;
        int e4 = (c & 15) * 4;
        float4 v = *(const float4*)(src + (size_t)(d0 + d) * DH_ + e4);
        Wf[d][e4+0] = v.x; Wf[d][e4+1] = v.y; Wf[d][e4+2] = v.z; Wf[d][e4+3] = v.w;
    }
    __syncthreads();
    u16* dst = Wt + (size_t)(which * H_ + h) * DH_ * D_;
    #pragma unroll
    for (int it = 0; it < 4; ++it){
        int e  = (c >> 4) + 16 * it;
        int d4 = (c & 15) * 4;
        u16 q[4];
        #pragma unroll
        for (int j = 0; j < 4; ++j)
            q[j] = h_bits((f16)(Wf[d4 + j][e] * 64.0f));
        u32* p = (u32*)(dst + (size_t)e * D_ + d0 + d4);
        p[0] = q[0] | ((u32)q[1] << 16);
        p[1] = q[2] | ((u32)q[3] << 16);
    }
}

// ---------------------------------------------------------------------------
// Kernel 2: proj — R0 structure (proven 64.4 us twice; both 8-phase ports
// measured slower).  128x128 tiles, 4 waves, BK=32, PKS=40, reg prefetch.
// ---------------------------------------------------------------------------
#define PKS 40

__global__ __launch_bounds__(256, 3) void proj_kernel(
    const u16* __restrict__ Xhi, const u16* __restrict__ Xlo,
    const u16* __restrict__ Wt,
    const float* __restrict__ bq, const float* __restrict__ bk,
    const float* __restrict__ bv,
    f16* __restrict__ Qh, f16* __restrict__ Kh, f16* __restrict__ Vt)
{
    __shared__ u16 XsHi[128 * PKS], XsLo[128 * PKS], Bs[128 * PKS];

    const int tid  = threadIdx.x;
    const int lane = tid & 63;
    const int w    = tid >> 6;
    const int quad = lane >> 4;
    const int ln   = lane & 15;
    const int wr   = (w >> 1) * 64;
    const int wc   = (w & 1) * 64;
    const int m0   = blockIdx.x * 128;
    const int c0   = blockIdx.y * 128;

    const int sr  = tid >> 2;          // 0..63
    const int sch = (tid & 3) * 8;     // 0,8,16,24

    const u16* xh0 = Xhi + (size_t)(m0 + sr) * D_ + sch;
    const u16* xh1 = xh0 + (size_t)64 * D_;
    const u16* xl0 = Xlo + (size_t)(m0 + sr) * D_ + sch;
    const u16* xl1 = xl0 + (size_t)64 * D_;
    const u16* wb0 = Wt  + (size_t)(c0 + sr) * D_ + sch;
    const u16* wb1 = wb0 + (size_t)64 * D_;

    uint4 rh0 = *(const uint4*)xh0, rh1 = *(const uint4*)xh1;
    uint4 rl0 = *(const uint4*)xl0, rl1 = *(const uint4*)xl1;
    uint4 rw0 = *(const uint4*)wb0, rw1 = *(const uint4*)wb1;

    f32x4 acc[4][4];
    #pragma unroll
    for (int i = 0; i < 4; ++i)
        #pragma unroll
        for (int j = 0; j < 4; ++j)
            acc[i][j] = (f32x4){0.f, 0.f, 0.f, 0.f};

    for (int k0 = 0; k0 < D_; k0 += 32){
        __syncthreads();
        *(uint4*)&XsHi[sr * PKS + sch]        = rh0;
        *(uint4*)&XsHi[(sr + 64) * PKS + sch] = rh1;
        *(uint4*)&XsLo[sr * PKS + sch]        = rl0;
        *(uint4*)&XsLo[(sr + 64) * PKS + sch] = rl1;
        *(uint4*)&Bs[sr * PKS + sch]          = rw0;
        *(uint4*)&Bs[(sr + 64) * PKS + sch]   = rw1;
        const int kn = k0 + 32;
        if (kn < D_){
            rh0 = *(const uint4*)(xh0 + kn); rh1 = *(const uint4*)(xh1 + kn);
            rl0 = *(const uint4*)(xl0 + kn); rl1 = *(const uint4*)(xl1 + kn);
            rw0 = *(const uint4*)(wb0 + kn); rw1 = *(const uint4*)(wb1 + kn);
        }
        __syncthreads();

        half8 ahi[4], alo[4], bf[4];
        #pragma unroll
        for (int mt = 0; mt < 4; ++mt){
            int row = wr + 16 * mt + ln;
            ahi[mt] = __builtin_bit_cast(half8, *(const uint4*)&XsHi[row * PKS + quad * 8]);
            alo[mt] = __builtin_bit_cast(half8, *(const uint4*)&XsLo[row * PKS + quad * 8]);
        }
        #pragma unroll
        for (int nt = 0; nt < 4; ++nt)
            bf[nt] = __builtin_bit_cast(half8,
                *(const uint4*)&Bs[(wc + 16 * nt + ln) * PKS + quad * 8]);
        #pragma unroll
        for (int mt = 0; mt < 4; ++mt)
            #pragma unroll
            for (int nt = 0; nt < 4; ++nt){
                acc[mt][nt] = __builtin_amdgcn_mfma_f32_16x16x32_f16(ahi[mt], bf[nt], acc[mt][nt], 0, 0, 0);
                acc[mt][nt] = __builtin_amdgcn_mfma_f32_16x16x32_f16(alo[mt], bf[nt], acc[mt][nt], 0, 0, 0);
            }
    }

    const float QSCALE = 0.125f * 1.44269504088896340736f;
    const float INV64  = 0.015625f;
    #pragma unroll
    for (int nt = 0; nt < 4; ++nt){
        int colg  = c0 + wc + 16 * nt + ln;
        int which = colg >> 10;          // uniform within the 16-col group
        int h     = (colg >> 6) & 15;    // uniform within the 16-col group
        int e     = colg & 63;
        const float* bp = (which == 0) ? bq : (which == 1) ? bk : bv;
        float bias = bp[h * DH_ + e];
        if (which < 2){
            f16* op = (which == 0) ? Qh : Kh;
            float scale = (which == 0) ? QSCALE : 1.0f;
            #pragma unroll
            for (int mt = 0; mt < 4; ++mt)
                #pragma unroll
                for (int r = 0; r < 4; ++r){
                    int sg = m0 + wr + 16 * mt + 4 * quad + r;
                    int b  = sg >> 11;
                    int s  = sg & (S_ - 1);
                    float val = (acc[mt][nt][r] * INV64 + bias) * scale;
                    op[((size_t)(b * H_ + h) * S_ + s) * DH_ + e] = (f16)val;
                }
        } else {
            // V: write transposed Vt[bh][e][t]; 4 consecutive s -> 8B store
            #pragma unroll
            for (int mt = 0; mt < 4; ++mt){
                int sg0 = m0 + wr + 16 * mt + 4 * quad;
                int b   = sg0 >> 11;
                int s0  = sg0 & (S_ - 1);
                u16 p[4];
                #pragma unroll
                for (int r = 0; r < 4; ++r)
                    p[r] = h_bits((f16)(acc[mt][nt][r] * INV64 + bias));
                uint2 pk;
                pk.x = p[0] | ((u32)p[1] << 16);
                pk.y = p[2] | ((u32)p[3] << 16);
                *(uint2*)((u16*)Vt + ((size_t)((b * H_ + h) * DH_ + e)) * S_ + s0) = pk;
            }
        }
    }
}

// ---------------------------------------------------------------------------
// Kernel 3 (R4): R0 attention geometry (16 q/wave, grid (32,32), proven
// < 64 us) with DOUBLE-BUFFERED K/V LDS -> ONE barrier per 64-t tile
// (R0 had two).  Tile t's LDS data is written one iteration early, so the
// write->read stall vanishes and the global prefetch gains a full tile of
// slack.  Hazard audit: buf[nxt] writes (iter t) vs buf[nxt] reads
// (iter t-1) are separated by iter-t's barrier; buf[cur] writes (iter t-1)
// vs reads (iter t) likewise; waves can't skew >1 iteration (one barrier
// each).  Math order per q-row identical to R0 -> bit-identical output.
// T5 setprio(1) around the QK MFMA cluster (m191: helps independent-block
// attn).  LDS 36.9 KB, 4 blocks/CU (147.5 KB < 160).
// ---------------------------------------------------------------------------
#define AKS 72

__global__ __launch_bounds__(256, 4) void attn_kernel(
    const f16* __restrict__ Qh, const f16* __restrict__ Kh,
    const f16* __restrict__ Vt, float* __restrict__ Out)
{
    __shared__ u16 Ks[2][64 * AKS];   // K tile [t][e], double-buffered
    __shared__ u16 Vs[2][64 * AKS];   // V tile [e][t], double-buffered

    const int tid  = threadIdx.x;
    const int lane = tid & 63;
    const int w    = tid >> 6;
    const int quad = lane >> 4;
    const int ln   = lane & 15;
    const int hb   = blockIdx.x;            // b*H + h  (XCD = hb % 8)
    const int i    = blockIdx.y;            // pair index
    const int h    = hb & 15;
    const int b    = hb >> 4;
    const int bh   = hb;
    const int sub  = w & 1;
    const int qbase = (w >> 1) ? (S_ - 32 * (i + 1) + 16 * sub)
                               : (32 * i + 16 * sub);
    const int vmax  = S_ - 32 * i - 1;      // highest t any wave's PV needs

    const u16* Qg = (const u16*)Qh + (size_t)bh * S_ * DH_;
    const u16* Kg = (const u16*)Kh + (size_t)bh * S_ * DH_;
    const u16* Vg = (const u16*)Vt + (size_t)bh * DH_ * S_;

    // Q fragments straight from global (B-operand: n=q=ln, k=d=32ks+8quad+j)
    half8 qf[2];
    #pragma unroll
    for (int ks = 0; ks < 2; ++ks)
        qf[ks] = __builtin_bit_cast(half8,
            *(const uint4*)(Qg + (size_t)(qbase + ln) * DH_ + 32 * ks + 8 * quad));

    // staging coords: thread covers K rows kr,kr+32 / V rows (e) kr,kr+32
    const int kr = tid >> 3;
    const int kc = (tid & 7) * 8;

    // tile 0 into regs, then straight into buf0 (visible after first barrier)
    uint4 kA = *(const uint4*)(Kg + (size_t)kr * DH_ + kc);
    uint4 kB = *(const uint4*)(Kg + (size_t)(kr + 32) * DH_ + kc);
    uint4 vA = *(const uint4*)(Vg + (size_t)kr * S_ + kc);
    uint4 vB = *(const uint4*)(Vg + (size_t)(kr + 32) * S_ + kc);

    *(uint4*)&Ks[0][kr * AKS + kc]        = kA;
    *(uint4*)&Ks[0][(kr + 32) * AKS + kc] = kB;
    *(uint4*)&Vs[0][kr * AKS + kc]        = vA;   // 0 <= vmax always
    *(uint4*)&Vs[0][(kr + 32) * AKS + kc] = vB;

    // prefetch tile 1 into regs
    {
        const int tn = 64;
        kA = *(const uint4*)(Kg + (size_t)(tn + kr) * DH_ + kc);
        kB = *(const uint4*)(Kg + (size_t)(tn + kr + 32) * DH_ + kc);
        if (tn <= vmax){
            vA = *(const uint4*)(Vg + (size_t)kr * S_ + tn + kc);
            vB = *(const uint4*)(Vg + (size_t)(kr + 32) * S_ + tn + kc);
        }
    }

    float l_r = 0.f;
    f32x4 o_acc[4];
    #pragma unroll
    for (int nt = 0; nt < 4; ++nt) o_acc[nt] = (f32x4){0.f, 0.f, 0.f, 0.f};

    const int qrow   = qbase + ln;     // this lane's q (n-dim)
    const int pv_lim = qbase + 15;     // wave-uniform PV bound

    for (int t0 = 0; t0 < S_; t0 += 64){
        const int cur = (t0 >> 6) & 1;
        const u16* Kc = Ks[cur];
        const u16* Vc = Vs[cur];
        u16* Kn = Ks[cur ^ 1];
        u16* Vn = Vs[cur ^ 1];

        __syncthreads();   // buf[cur] writes (prev iter) visible; buf[nxt]
                           // readers (prev iter) retired -> safe to overwrite

        // write tile t0+64 into buf[nxt] (overlaps with this tile's compute)
        const int tn = t0 + 64;
        if (tn < S_){
            *(uint4*)&Kn[kr * AKS + kc]        = kA;
            *(uint4*)&Kn[(kr + 32) * AKS + kc] = kB;
            if (tn <= vmax){
                *(uint4*)&Vn[kr * AKS + kc]        = vA;
                *(uint4*)&Vn[(kr + 32) * AKS + kc] = vB;
            }
        }
        // prefetch tile t0+128 into regs
        const int tp = t0 + 128;
        if (tp < S_){
            kA = *(const uint4*)(Kg + (size_t)(tp + kr) * DH_ + kc);
            kB = *(const uint4*)(Kg + (size_t)(tp + kr + 32) * DH_ + kc);
            if (tp <= vmax){
                vA = *(const uint4*)(Vg + (size_t)kr * S_ + tp + kc);
                vB = *(const uint4*)(Vg + (size_t)(kr + 32) * S_ + tp + kc);
            }
        }

        // S^T tile: A = K frags (m=t), B = Q frags (n=q), K=32 over d
        f32x4 sc[4];
        #pragma unroll
        for (int mt = 0; mt < 4; ++mt) sc[mt] = (f32x4){0.f, 0.f, 0.f, 0.f};
        __builtin_amdgcn_s_setprio(1);
        #pragma unroll
        for (int ks = 0; ks < 2; ++ks)
            #pragma unroll
            for (int mt = 0; mt < 4; ++mt){
                half8 kf = __builtin_bit_cast(half8,
                    *(const uint4*)&Kc[(16 * mt + ln) * AKS + 32 * ks + 8 * quad]);
                sc[mt] = __builtin_amdgcn_mfma_f32_16x16x32_f16(kf, qf[ks], sc[mt], 0, 0, 0);
            }
        __builtin_amdgcn_s_setprio(0);

        // p = exp2(s); denominator = plain running row-sum over ALL t
        #pragma unroll
        for (int mt = 0; mt < 4; ++mt)
            #pragma unroll
            for (int r = 0; r < 4; ++r)
                sc[mt][r] = EXP2(sc[mt][r]);
        float s = ((sc[0][0] + sc[0][1] + sc[0][2] + sc[0][3]) +
                   (sc[1][0] + sc[1][1] + sc[1][2] + sc[1][3])) +
                  ((sc[2][0] + sc[2][1] + sc[2][2] + sc[2][3]) +
                   (sc[3][0] + sc[3][1] + sc[3][2] + sc[3][3]));
        s += __shfl_xor(s, 16);
        s += __shfl_xor(s, 32);
        l_r += s;

        // PV per 16-t subtile; only the subtile starting AT qbase is partial
        #pragma unroll
        for (int mt = 0; mt < 4; ++mt){
            const int ts = t0 + 16 * mt;
            if (ts <= pv_lim){         // wave-uniform
                half4 pf;
                if (ts == qbase){      // wave-uniform: the one partial subtile
                    int tb = ts + 4 * quad;
                    #pragma unroll
                    for (int r = 0; r < 4; ++r)
                        pf[r] = (tb + r > qrow) ? (f16)0.f : (f16)sc[mt][r];
                } else {               // fully below diagonal: plain convert
                    #pragma unroll
                    for (int r = 0; r < 4; ++r)
                        pf[r] = (f16)sc[mt][r];
                }
                #pragma unroll
                for (int nt = 0; nt < 4; ++nt){
                    half4 vf = __builtin_bit_cast(half4,
                        *(const uint2*)&Vc[(16 * nt + ln) * AKS + 16 * mt + 4 * quad]);
                    o_acc[nt] = __builtin_amdgcn_mfma_f32_16x16x16f16(pf, vf, o_acc[nt], 0, 0, 0);
                }
            }
        }
    }

    // epilogue: o rows at q = qbase+4quad+r; l lives at lane ln=row
    #pragma unroll
    for (int r = 0; r < 4; ++r){
        float lv  = __shfl(l_r, (lane & 48) | (4 * quad + r));
        float inv = 1.0f / lv;
        int sg = qbase + 4 * quad + r;
        float* op = Out + ((size_t)b * S_ + sg) * D_ + h * DH_;
        #pragma unroll
        for (int nt = 0; nt < 4; ++nt)
            op[16 * nt + ln] = o_acc[nt][r] * inv;
    }
}

// ---------------------------------------------------------------------------
extern "C" void kernel_launch(void* const* d_in, const int* in_sizes, int n_in,
                              void* d_out, int out_size, void* d_ws, size_t ws_size,
                              hipStream_t stream)
{
    const float* X  = (const float*)d_in[0];
    const float* Wq = (const float*)d_in[1];
    const float* bq = (const float*)d_in[2];
    const float* Wk = (const float*)d_in[3];
    const float* bk = (const float*)d_in[4];
    const float* Wv = (const float*)d_in[5];
    const float* bv = (const float*)d_in[6];
    float* out = (float*)d_out;

    // workspace (46 MiB): Wt | Qh | Kh | Vt | Xhi | Xlo  (unchanged layout)
    u16* Wt  = (u16*)d_ws;                    // 3,145,728 u16
    f16* Qh  = (f16*)(Wt + 3145728);
    f16* Kh  = Qh + 4194304;
    f16* Vt  = Kh + 4194304;
    u16* Xhi = (u16*)(Vt + 4194304);
    u16* Xlo = Xhi + 4194304;

    prep_kernel<<<dim3(4096 + 768), 256, 0, stream>>>(X, Wq, Wk, Wv, Xhi, Xlo, Wt);
    proj_kernel<<<dim3(32, 24), 256, 0, stream>>>(Xhi, Xlo, Wt, bq, bk, bv, Qh, Kh, Vt);
    attn_kernel<<<dim3(32, 32), 256, 0, stream>>>(Qh, Kh, Vt, out);
}

// Round 6
// 191.258 us; speedup vs baseline: 1.2042x; 1.0206x over previous
//
#include <hip/hip_runtime.h>
#include <math.h>

#define B_  2
#define S_  2048
#define D_  1024
#define H_  16
#define DH_ 64

typedef unsigned short u16;
typedef unsigned int   u32;
typedef _Float16       f16;
typedef _Float16 half8  __attribute__((ext_vector_type(8)));
typedef _Float16 half4  __attribute__((ext_vector_type(4)));
typedef float    f32x4  __attribute__((ext_vector_type(4)));

#if __has_builtin(__builtin_amdgcn_exp2f)
#define EXP2(x) __builtin_amdgcn_exp2f(x)
#else
#define EXP2(x) exp2f(x)
#endif

__device__ __forceinline__ u16 h_bits(f16 h){ return __builtin_bit_cast(u16, h); }

// split 8 fp32 -> packed hi/lo f16 (bit-identical to the old prep path)
__device__ __forceinline__ void split8(float4 a, float4 b, uint4& H, uint4& L){
    float fv[8] = {a.x, a.y, a.z, a.w, b.x, b.y, b.z, b.w};
    u32 hw[4], lw[4];
    #pragma unroll
    for (int j = 0; j < 4; ++j){
        f16 h0 = (f16)fv[2*j],   h1 = (f16)fv[2*j+1];
        f16 l0 = (f16)(fv[2*j]   - (float)h0);
        f16 l1 = (f16)(fv[2*j+1] - (float)h1);
        hw[j] = h_bits(h0) | ((u32)h_bits(h1) << 16);
        lw[j] = h_bits(l0) | ((u32)h_bits(l1) << 16);
    }
    H = (uint4){hw[0], hw[1], hw[2], hw[3]};
    L = (uint4){lw[0], lw[1], lw[2], lw[3]};
}

// ---------------------------------------------------------------------------
// Kernel 1 (R5): prep = W transpose/convert ONLY (X-split fused into proj,
// saving ~64 MB of HBM traffic).  768 blocks.
// ---------------------------------------------------------------------------
__global__ __launch_bounds__(256) void prep_kernel(
    const float* __restrict__ Wq, const float* __restrict__ Wk,
    const float* __restrict__ Wv, u16* __restrict__ Wt)
{
    __shared__ float Wf[64][65];
    const int wb = blockIdx.x;          // 0..767
    const int c  = threadIdx.x;
    const int d0 = (wb & 15) * 64;
    const int h  = (wb >> 4) & 15;
    const int which = wb >> 8;
    const float* src = (which == 0) ? Wq : (which == 1) ? Wk : Wv;
    src += (size_t)h * D_ * DH_;

    #pragma unroll
    for (int it = 0; it < 4; ++it){
        int d  = (c >> 4) + 16 * it;
        int e4 = (c & 15) * 4;
        float4 v = *(const float4*)(src + (size_t)(d0 + d) * DH_ + e4);
        Wf[d][e4+0] = v.x; Wf[d][e4+1] = v.y; Wf[d][e4+2] = v.z; Wf[d][e4+3] = v.w;
    }
    __syncthreads();
    u16* dst = Wt + (size_t)(which * H_ + h) * DH_ * D_;
    #pragma unroll
    for (int it = 0; it < 4; ++it){
        int e  = (c >> 4) + 16 * it;
        int d4 = (c & 15) * 4;
        u16 q[4];
        #pragma unroll
        for (int j = 0; j < 4; ++j)
            q[j] = h_bits((f16)(Wf[d4 + j][e] * 64.0f));
        u32* p = (u32*)(dst + (size_t)e * D_ + d0 + d4);
        p[0] = q[0] | ((u32)q[1] << 16);
        p[1] = q[2] | ((u32)q[3] << 16);
    }
}

// ---------------------------------------------------------------------------
// Kernel 2 (R5): proj — proven R0 structure (128x128, 4 waves, BK=32,
// PKS=40, reg prefetch, 3 blocks/CU) with the X hi/lo split FUSED into
// staging.  X is read fp32 (same 4 B/elem as Xhi+Xlo was) and split
// in-register; the split for tile k+1 is placed AFTER the MFMA cluster so
// its vmcnt wait lands after a full compute phase and the VALU co-issues
// with MFMA (m114).  Staged values bit-identical to the old prep path.
// ---------------------------------------------------------------------------
#define PKS 40

__global__ __launch_bounds__(256, 3) void proj_kernel(
    const float* __restrict__ X,
    const u16* __restrict__ Wt,
    const float* __restrict__ bq, const float* __restrict__ bk,
    const float* __restrict__ bv,
    f16* __restrict__ Qh, f16* __restrict__ Kh, f16* __restrict__ Vt)
{
    __shared__ u16 XsHi[128 * PKS], XsLo[128 * PKS], Bs[128 * PKS];

    const int tid  = threadIdx.x;
    const int lane = tid & 63;
    const int w    = tid >> 6;
    const int quad = lane >> 4;
    const int ln   = lane & 15;
    const int wr   = (w >> 1) * 64;
    const int wc   = (w & 1) * 64;
    const int m0   = blockIdx.x * 128;
    const int c0   = blockIdx.y * 128;

    const int sr  = tid >> 2;          // 0..63
    const int sch = (tid & 3) * 8;     // 0,8,16,24

    const float* x0 = X + (size_t)(m0 + sr) * D_ + sch;
    const float* x1 = x0 + (size_t)64 * D_;
    const u16*  wb0 = Wt + (size_t)(c0 + sr) * D_ + sch;
    const u16*  wb1 = wb0 + (size_t)64 * D_;

    // prologue: load tile0 raw + W, convert tile0
    float4 p00 = *(const float4*)x0, p01 = *(const float4*)(x0 + 4);
    float4 p10 = *(const float4*)x1, p11 = *(const float4*)(x1 + 4);
    uint4 rw0 = *(const uint4*)wb0, rw1 = *(const uint4*)wb1;
    uint4 h0, l0, h1, l1;
    split8(p00, p01, h0, l0);
    split8(p10, p11, h1, l1);

    f32x4 acc[4][4];
    #pragma unroll
    for (int i = 0; i < 4; ++i)
        #pragma unroll
        for (int j = 0; j < 4; ++j)
            acc[i][j] = (f32x4){0.f, 0.f, 0.f, 0.f};

    for (int k0 = 0; k0 < D_; k0 += 32){
        __syncthreads();
        *(uint4*)&XsHi[sr * PKS + sch]        = h0;
        *(uint4*)&XsHi[(sr + 64) * PKS + sch] = h1;
        *(uint4*)&XsLo[sr * PKS + sch]        = l0;
        *(uint4*)&XsLo[(sr + 64) * PKS + sch] = l1;
        *(uint4*)&Bs[sr * PKS + sch]          = rw0;
        *(uint4*)&Bs[(sr + 64) * PKS + sch]   = rw1;
        const int kn = k0 + 32;
        if (kn < D_){
            p00 = *(const float4*)(x0 + kn); p01 = *(const float4*)(x0 + kn + 4);
            p10 = *(const float4*)(x1 + kn); p11 = *(const float4*)(x1 + kn + 4);
            rw0 = *(const uint4*)(wb0 + kn); rw1 = *(const uint4*)(wb1 + kn);
        }
        __syncthreads();

        half8 ahi[4], alo[4], bf[4];
        #pragma unroll
        for (int mt = 0; mt < 4; ++mt){
            int row = wr + 16 * mt + ln;
            ahi[mt] = __builtin_bit_cast(half8, *(const uint4*)&XsHi[row * PKS + quad * 8]);
            alo[mt] = __builtin_bit_cast(half8, *(const uint4*)&XsLo[row * PKS + quad * 8]);
        }
        #pragma unroll
        for (int nt = 0; nt < 4; ++nt)
            bf[nt] = __builtin_bit_cast(half8,
                *(const uint4*)&Bs[(wc + 16 * nt + ln) * PKS + quad * 8]);
        #pragma unroll
        for (int mt = 0; mt < 4; ++mt)
            #pragma unroll
            for (int nt = 0; nt < 4; ++nt){
                acc[mt][nt] = __builtin_amdgcn_mfma_f32_16x16x32_f16(ahi[mt], bf[nt], acc[mt][nt], 0, 0, 0);
                acc[mt][nt] = __builtin_amdgcn_mfma_f32_16x16x32_f16(alo[mt], bf[nt], acc[mt][nt], 0, 0, 0);
            }

        // convert tile k+1 AFTER the MFMA cluster: loads have had the whole
        // compute phase to land; VALU co-issues with MFMA.
        if (kn < D_){
            split8(p00, p01, h0, l0);
            split8(p10, p11, h1, l1);
        }
    }

    const float QSCALE = 0.125f * 1.44269504088896340736f;
    const float INV64  = 0.015625f;
    #pragma unroll
    for (int nt = 0; nt < 4; ++nt){
        int colg  = c0 + wc + 16 * nt + ln;
        int which = colg >> 10;          // uniform within the 16-col group
        int h     = (colg >> 6) & 15;    // uniform within the 16-col group
        int e     = colg & 63;
        const float* bp = (which == 0) ? bq : (which == 1) ? bk : bv;
        float bias = bp[h * DH_ + e];
        if (which < 2){
            f16* op = (which == 0) ? Qh : Kh;
            float scale = (which == 0) ? QSCALE : 1.0f;
            #pragma unroll
            for (int mt = 0; mt < 4; ++mt)
                #pragma unroll
                for (int r = 0; r < 4; ++r){
                    int sg = m0 + wr + 16 * mt + 4 * quad + r;
                    int b  = sg >> 11;
                    int s  = sg & (S_ - 1);
                    float val = (acc[mt][nt][r] * INV64 + bias) * scale;
                    op[((size_t)(b * H_ + h) * S_ + s) * DH_ + e] = (f16)val;
                }
        } else {
            // V: write transposed Vt[bh][e][t]; 4 consecutive s -> 8B store
            #pragma unroll
            for (int mt = 0; mt < 4; ++mt){
                int sg0 = m0 + wr + 16 * mt + 4 * quad;
                int b   = sg0 >> 11;
                int s0  = sg0 & (S_ - 1);
                u16 p[4];
                #pragma unroll
                for (int r = 0; r < 4; ++r)
                    p[r] = h_bits((f16)(acc[mt][nt][r] * INV64 + bias));
                uint2 pk;
                pk.x = p[0] | ((u32)p[1] << 16);
                pk.y = p[2] | ((u32)p[3] << 16);
                *(uint2*)((u16*)Vt + ((size_t)((b * H_ + h) * DH_ + e)) * S_ + s0) = pk;
            }
        }
    }
}

// ---------------------------------------------------------------------------
// Kernel 3: attention — EXACT R0 version (the only attn ever measured inside
// a 189 us total; R3 and R4 variants both regressed).
// ---------------------------------------------------------------------------
#define AKS 72

__global__ __launch_bounds__(256, 4) void attn_kernel(
    const f16* __restrict__ Qh, const f16* __restrict__ Kh,
    const f16* __restrict__ Vt, float* __restrict__ Out)
{
    __shared__ u16 Ks[64 * AKS];   // K tile [t][e]
    __shared__ u16 Vs[64 * AKS];   // V tile [e][t]

    const int tid  = threadIdx.x;
    const int lane = tid & 63;
    const int w    = tid >> 6;
    const int quad = lane >> 4;
    const int ln   = lane & 15;
    const int hb   = blockIdx.x;            // b*H + h  (XCD = hb % 8)
    const int i    = blockIdx.y;            // pair index
    const int h    = hb & 15;
    const int b    = hb >> 4;
    const int bh   = hb;
    const int sub  = w & 1;
    const int qbase = (w >> 1) ? (S_ - 32 * (i + 1) + 16 * sub)
                               : (32 * i + 16 * sub);
    const int vmax  = S_ - 32 * i - 1;      // highest t any wave's PV needs

    const u16* Qg = (const u16*)Qh + (size_t)bh * S_ * DH_;
    const u16* Kg = (const u16*)Kh + (size_t)bh * S_ * DH_;
    const u16* Vg = (const u16*)Vt + (size_t)bh * DH_ * S_;

    // Q fragments straight from global (B-operand: n=q=ln, k=d=32ks+8quad+j)
    half8 qf[2];
    #pragma unroll
    for (int ks = 0; ks < 2; ++ks)
        qf[ks] = __builtin_bit_cast(half8,
            *(const uint4*)(Qg + (size_t)(qbase + ln) * DH_ + 32 * ks + 8 * quad));

    // staging coords: thread covers K rows kr,kr+32 / V rows (e) kr,kr+32
    const int kr = tid >> 3;
    const int kc = (tid & 7) * 8;

    // prefetch tile 0 into registers
    uint4 kA = *(const uint4*)(Kg + (size_t)kr * DH_ + kc);
    uint4 kB = *(const uint4*)(Kg + (size_t)(kr + 32) * DH_ + kc);
    uint4 vA = *(const uint4*)(Vg + (size_t)kr * S_ + kc);
    uint4 vB = *(const uint4*)(Vg + (size_t)(kr + 32) * S_ + kc);

    float l_r = 0.f;
    f32x4 o_acc[4];
    #pragma unroll
    for (int nt = 0; nt < 4; ++nt) o_acc[nt] = (f32x4){0.f, 0.f, 0.f, 0.f};

    const int qrow   = qbase + ln;     // this lane's q (n-dim)
    const int pv_lim = qbase + 15;     // wave-uniform PV bound

    for (int t0 = 0; t0 < S_; t0 += 64){
        __syncthreads();               // all waves done reading prev tile
        *(uint4*)&Ks[kr * AKS + kc]        = kA;
        *(uint4*)&Ks[(kr + 32) * AKS + kc] = kB;
        if (t0 <= vmax){
            *(uint4*)&Vs[kr * AKS + kc]        = vA;
            *(uint4*)&Vs[(kr + 32) * AKS + kc] = vB;
        }
        // prefetch tile t0+64 (hidden behind this tile's compute)
        const int tn = t0 + 64;
        if (tn < S_){
            kA = *(const uint4*)(Kg + (size_t)(tn + kr) * DH_ + kc);
            kB = *(const uint4*)(Kg + (size_t)(tn + kr + 32) * DH_ + kc);
            if (tn <= vmax){
                vA = *(const uint4*)(Vg + (size_t)kr * S_ + tn + kc);
                vB = *(const uint4*)(Vg + (size_t)(kr + 32) * S_ + tn + kc);
            }
        }
        __syncthreads();               // LDS tile ready

        // S^T tile: A = K frags (m=t), B = Q frags (n=q), K=32 over d
        f32x4 sc[4];
        #pragma unroll
        for (int mt = 0; mt < 4; ++mt) sc[mt] = (f32x4){0.f, 0.f, 0.f, 0.f};
        #pragma unroll
        for (int ks = 0; ks < 2; ++ks)
            #pragma unroll
            for (int mt = 0; mt < 4; ++mt){
                half8 kf = __builtin_bit_cast(half8,
                    *(const uint4*)&Ks[(16 * mt + ln) * AKS + 32 * ks + 8 * quad]);
                sc[mt] = __builtin_amdgcn_mfma_f32_16x16x32_f16(kf, qf[ks], sc[mt], 0, 0, 0);
            }

        // p = exp2(s); denominator = plain running row-sum over ALL t
        #pragma unroll
        for (int mt = 0; mt < 4; ++mt)
            #pragma unroll
            for (int r = 0; r < 4; ++r)
                sc[mt][r] = EXP2(sc[mt][r]);
        float s = ((sc[0][0] + sc[0][1] + sc[0][2] + sc[0][3]) +
                   (sc[1][0] + sc[1][1] + sc[1][2] + sc[1][3])) +
                  ((sc[2][0] + sc[2][1] + sc[2][2] + sc[2][3]) +
                   (sc[3][0] + sc[3][1] + sc[3][2] + sc[3][3]));
        s += __shfl_xor(s, 16);
        s += __shfl_xor(s, 32);
        l_r += s;

        // PV per 16-t subtile; only the subtile starting AT qbase is partial
        #pragma unroll
        for (int mt = 0; mt < 4; ++mt){
            const int ts = t0 + 16 * mt;
            if (ts <= pv_lim){         // wave-uniform
                half4 pf;
                if (ts == qbase){      // wave-uniform: the one partial subtile
                    int tb = ts + 4 * quad;
                    #pragma unroll
                    for (int r = 0; r < 4; ++r)
                        pf[r] = (tb + r > qrow) ? (f16)0.f : (f16)sc[mt][r];
                } else {               // fully below diagonal: plain convert
                    #pragma unroll
                    for (int r = 0; r < 4; ++r)
                        pf[r] = (f16)sc[mt][r];
                }
                #pragma unroll
                for (int nt = 0; nt < 4; ++nt){
                    half4 vf = __builtin_bit_cast(half4,
                        *(const uint2*)&Vs[(16 * nt + ln) * AKS + 16 * mt + 4 * quad]);
                    o_acc[nt] = __builtin_amdgcn_mfma_f32_16x16x16f16(pf, vf, o_acc[nt], 0, 0, 0);
                }
            }
        }
    }

    // epilogue: o rows at q = qbase+4quad+r; l lives at lane ln=row
    #pragma unroll
    for (int r = 0; r < 4; ++r){
        float lv  = __shfl(l_r, (lane & 48) | (4 * quad + r));
        float inv = 1.0f / lv;
        int sg = qbase + 4 * quad + r;
        float* op = Out + ((size_t)b * S_ + sg) * D_ + h * DH_;
        #pragma unroll
        for (int nt = 0; nt < 4; ++nt)
            op[16 * nt + ln] = o_acc[nt][r] * inv;
    }
}

// ---------------------------------------------------------------------------
extern "C" void kernel_launch(void* const* d_in, const int* in_sizes, int n_in,
                              void* d_out, int out_size, void* d_ws, size_t ws_size,
                              hipStream_t stream)
{
    const float* X  = (const float*)d_in[0];
    const float* Wq = (const float*)d_in[1];
    const float* bq = (const float*)d_in[2];
    const float* Wk = (const float*)d_in[3];
    const float* bk = (const float*)d_in[4];
    const float* Wv = (const float*)d_in[5];
    const float* bv = (const float*)d_in[6];
    float* out = (float*)d_out;

    // workspace (~31.5 MiB): Wt | Qh | Kh | Vt   (Xhi/Xlo eliminated)
    u16* Wt  = (u16*)d_ws;                    // 3,145,728 u16
    f16* Qh  = (f16*)(Wt + 3145728);
    f16* Kh  = Qh + 4194304;
    f16* Vt  = Kh + 4194304;

    prep_kernel<<<dim3(768), 256, 0, stream>>>(Wq, Wk, Wv, Wt);
    proj_kernel<<<dim3(32, 24), 256, 0, stream>>>(X, Wt, bq, bk, bv, Qh, Kh, Vt);
    attn_kernel<<<dim3(32, 32), 256, 0, stream>>>(Qh, Kh, Vt, out);
}

// Round 7
// 190.913 us; speedup vs baseline: 1.2064x; 1.0018x over previous
//
#include <hip/hip_runtime.h>
#include <math.h>

#define B_  2
#define S_  2048
#define D_  1024
#define H_  16
#define DH_ 64

typedef unsigned short u16;
typedef unsigned int   u32;
typedef _Float16       f16;
typedef _Float16 half8  __attribute__((ext_vector_type(8)));
typedef _Float16 half4  __attribute__((ext_vector_type(4)));
typedef float    f32x4  __attribute__((ext_vector_type(4)));

#if __has_builtin(__builtin_amdgcn_exp2f)
#define EXP2(x) __builtin_amdgcn_exp2f(x)
#else
#define EXP2(x) exp2f(x)
#endif

__device__ __forceinline__ u16 h_bits(f16 h){ return __builtin_bit_cast(u16, h); }

// split 8 fp32 -> packed hi/lo f16 (bit-identical to the old prep path)
__device__ __forceinline__ void split8(float4 a, float4 b, uint4& H, uint4& L){
    float fv[8] = {a.x, a.y, a.z, a.w, b.x, b.y, b.z, b.w};
    u32 hw[4], lw[4];
    #pragma unroll
    for (int j = 0; j < 4; ++j){
        f16 h0 = (f16)fv[2*j],   h1 = (f16)fv[2*j+1];
        f16 l0 = (f16)(fv[2*j]   - (float)h0);
        f16 l1 = (f16)(fv[2*j+1] - (float)h1);
        hw[j] = h_bits(h0) | ((u32)h_bits(h1) << 16);
        lw[j] = h_bits(l0) | ((u32)h_bits(l1) << 16);
    }
    H = (uint4){hw[0], hw[1], hw[2], hw[3]};
    L = (uint4){lw[0], lw[1], lw[2], lw[3]};
}

// ---------------------------------------------------------------------------
// Kernel 1: prep = W transpose/convert only (UNCHANGED from R6).
// ---------------------------------------------------------------------------
__global__ __launch_bounds__(256) void prep_kernel(
    const float* __restrict__ Wq, const float* __restrict__ Wk,
    const float* __restrict__ Wv, u16* __restrict__ Wt)
{
    __shared__ float Wf[64][65];
    const int wb = blockIdx.x;          // 0..767
    const int c  = threadIdx.x;
    const int d0 = (wb & 15) * 64;
    const int h  = (wb >> 4) & 15;
    const int which = wb >> 8;
    const float* src = (which == 0) ? Wq : (which == 1) ? Wk : Wv;
    src += (size_t)h * D_ * DH_;

    #pragma unroll
    for (int it = 0; it < 4; ++it){
        int d  = (c >> 4) + 16 * it;
        int e4 = (c & 15) * 4;
        float4 v = *(const float4*)(src + (size_t)(d0 + d) * DH_ + e4);
        Wf[d][e4+0] = v.x; Wf[d][e4+1] = v.y; Wf[d][e4+2] = v.z; Wf[d][e4+3] = v.w;
    }
    __syncthreads();
    u16* dst = Wt + (size_t)(which * H_ + h) * DH_ * D_;
    #pragma unroll
    for (int it = 0; it < 4; ++it){
        int e  = (c >> 4) + 16 * it;
        int d4 = (c & 15) * 4;
        u16 q[4];
        #pragma unroll
        for (int j = 0; j < 4; ++j)
            q[j] = h_bits((f16)(Wf[d4 + j][e] * 64.0f));
        u32* p = (u32*)(dst + (size_t)e * D_ + d0 + d4);
        p[0] = q[0] | ((u32)q[1] << 16);
        p[1] = q[2] | ((u32)q[3] << 16);
    }
}

// ---------------------------------------------------------------------------
// Kernel 2: proj — UNCHANGED from R6 (R0 GEMM structure + fused X split;
// measured 65.3 us, split VALU co-issues under MFMA).
// ---------------------------------------------------------------------------
#define PKS 40

__global__ __launch_bounds__(256, 3) void proj_kernel(
    const float* __restrict__ X,
    const u16* __restrict__ Wt,
    const float* __restrict__ bq, const float* __restrict__ bk,
    const float* __restrict__ bv,
    f16* __restrict__ Qh, f16* __restrict__ Kh, f16* __restrict__ Vt)
{
    __shared__ u16 XsHi[128 * PKS], XsLo[128 * PKS], Bs[128 * PKS];

    const int tid  = threadIdx.x;
    const int lane = tid & 63;
    const int w    = tid >> 6;
    const int quad = lane >> 4;
    const int ln   = lane & 15;
    const int wr   = (w >> 1) * 64;
    const int wc   = (w & 1) * 64;
    const int m0   = blockIdx.x * 128;
    const int c0   = blockIdx.y * 128;

    const int sr  = tid >> 2;          // 0..63
    const int sch = (tid & 3) * 8;     // 0,8,16,24

    const float* x0 = X + (size_t)(m0 + sr) * D_ + sch;
    const float* x1 = x0 + (size_t)64 * D_;
    const u16*  wb0 = Wt + (size_t)(c0 + sr) * D_ + sch;
    const u16*  wb1 = wb0 + (size_t)64 * D_;

    // prologue: load tile0 raw + W, convert tile0
    float4 p00 = *(const float4*)x0, p01 = *(const float4*)(x0 + 4);
    float4 p10 = *(const float4*)x1, p11 = *(const float4*)(x1 + 4);
    uint4 rw0 = *(const uint4*)wb0, rw1 = *(const uint4*)wb1;
    uint4 h0, l0, h1, l1;
    split8(p00, p01, h0, l0);
    split8(p10, p11, h1, l1);

    f32x4 acc[4][4];
    #pragma unroll
    for (int i = 0; i < 4; ++i)
        #pragma unroll
        for (int j = 0; j < 4; ++j)
            acc[i][j] = (f32x4){0.f, 0.f, 0.f, 0.f};

    for (int k0 = 0; k0 < D_; k0 += 32){
        __syncthreads();
        *(uint4*)&XsHi[sr * PKS + sch]        = h0;
        *(uint4*)&XsHi[(sr + 64) * PKS + sch] = h1;
        *(uint4*)&XsLo[sr * PKS + sch]        = l0;
        *(uint4*)&XsLo[(sr + 64) * PKS + sch] = l1;
        *(uint4*)&Bs[sr * PKS + sch]          = rw0;
        *(uint4*)&Bs[(sr + 64) * PKS + sch]   = rw1;
        const int kn = k0 + 32;
        if (kn < D_){
            p00 = *(const float4*)(x0 + kn); p01 = *(const float4*)(x0 + kn + 4);
            p10 = *(const float4*)(x1 + kn); p11 = *(const float4*)(x1 + kn + 4);
            rw0 = *(const uint4*)(wb0 + kn); rw1 = *(const uint4*)(wb1 + kn);
        }
        __syncthreads();

        half8 ahi[4], alo[4], bf[4];
        #pragma unroll
        for (int mt = 0; mt < 4; ++mt){
            int row = wr + 16 * mt + ln;
            ahi[mt] = __builtin_bit_cast(half8, *(const uint4*)&XsHi[row * PKS + quad * 8]);
            alo[mt] = __builtin_bit_cast(half8, *(const uint4*)&XsLo[row * PKS + quad * 8]);
        }
        #pragma unroll
        for (int nt = 0; nt < 4; ++nt)
            bf[nt] = __builtin_bit_cast(half8,
                *(const uint4*)&Bs[(wc + 16 * nt + ln) * PKS + quad * 8]);
        #pragma unroll
        for (int mt = 0; mt < 4; ++mt)
            #pragma unroll
            for (int nt = 0; nt < 4; ++nt){
                acc[mt][nt] = __builtin_amdgcn_mfma_f32_16x16x32_f16(ahi[mt], bf[nt], acc[mt][nt], 0, 0, 0);
                acc[mt][nt] = __builtin_amdgcn_mfma_f32_16x16x32_f16(alo[mt], bf[nt], acc[mt][nt], 0, 0, 0);
            }

        // convert tile k+1 AFTER the MFMA cluster: loads have had the whole
        // compute phase to land; VALU co-issues with MFMA.
        if (kn < D_){
            split8(p00, p01, h0, l0);
            split8(p10, p11, h1, l1);
        }
    }

    const float QSCALE = 0.125f * 1.44269504088896340736f;
    const float INV64  = 0.015625f;
    #pragma unroll
    for (int nt = 0; nt < 4; ++nt){
        int colg  = c0 + wc + 16 * nt + ln;
        int which = colg >> 10;          // uniform within the 16-col group
        int h     = (colg >> 6) & 15;    // uniform within the 16-col group
        int e     = colg & 63;
        const float* bp = (which == 0) ? bq : (which == 1) ? bk : bv;
        float bias = bp[h * DH_ + e];
        if (which < 2){
            f16* op = (which == 0) ? Qh : Kh;
            float scale = (which == 0) ? QSCALE : 1.0f;
            #pragma unroll
            for (int mt = 0; mt < 4; ++mt)
                #pragma unroll
                for (int r = 0; r < 4; ++r){
                    int sg = m0 + wr + 16 * mt + 4 * quad + r;
                    int b  = sg >> 11;
                    int s  = sg & (S_ - 1);
                    float val = (acc[mt][nt][r] * INV64 + bias) * scale;
                    op[((size_t)(b * H_ + h) * S_ + s) * DH_ + e] = (f16)val;
                }
        } else {
            // V: write transposed Vt[bh][e][t]; 4 consecutive s -> 8B store
            #pragma unroll
            for (int mt = 0; mt < 4; ++mt){
                int sg0 = m0 + wr + 16 * mt + 4 * quad;
                int b   = sg0 >> 11;
                int s0  = sg0 & (S_ - 1);
                u16 p[4];
                #pragma unroll
                for (int r = 0; r < 4; ++r)
                    p[r] = h_bits((f16)(acc[mt][nt][r] * INV64 + bias));
                uint2 pk;
                pk.x = p[0] | ((u32)p[1] << 16);
                pk.y = p[2] | ((u32)p[3] << 16);
                *(uint2*)((u16*)Vt + ((size_t)((b * H_ + h) * DH_ + e)) * S_ + s0) = pk;
            }
        }
    }
}

// ---------------------------------------------------------------------------
// Kernel 3 (R7): attention, R0 geometry (16 q/wave, grid (32,32), 4 waves,
// 4 blocks/CU) with BK=128: TWO 64-t sub-tiles per barrier pair.  Keeps the
// proven 2-barrier staging structure (R4's 1-barrier dbuf regressed) but
// halves barrier count (64 -> 32 per block) and doubles prefetch slack.
// Per-q-row t-order identical to R0 (sub A then sub B = successive R0
// iterations) -> bit-identical output.  LDS: K [128][72] 18.4 KB +
// V [64][136] 17.4 KB = 35.9 KB; x4 blocks = 143.5 KB < 160.  Staging regs
// 8x uint4 (+16 VGPR vs R0, ~110 total, under the 128 cap of (256,4)).
// ---------------------------------------------------------------------------
#define AKS 72
#define VKS 136

__global__ __launch_bounds__(256, 4) void attn_kernel(
    const f16* __restrict__ Qh, const f16* __restrict__ Kh,
    const f16* __restrict__ Vt, float* __restrict__ Out)
{
    __shared__ u16 Ks[128 * AKS];   // K tile [t(128)][e(64)+pad]
    __shared__ u16 Vs[64 * VKS];    // V tile [e(64)][t(128)+pad]

    const int tid  = threadIdx.x;
    const int lane = tid & 63;
    const int w    = tid >> 6;
    const int quad = lane >> 4;
    const int ln   = lane & 15;
    const int hb   = blockIdx.x;            // b*H + h  (XCD = hb % 8)
    const int i    = blockIdx.y;            // pair index
    const int h    = hb & 15;
    const int b    = hb >> 4;
    const int bh   = hb;
    const int sub  = w & 1;
    const int qbase = (w >> 1) ? (S_ - 32 * (i + 1) + 16 * sub)
                               : (32 * i + 16 * sub);
    const int vmax  = S_ - 32 * i - 1;      // highest t any wave's PV needs

    const u16* Qg = (const u16*)Qh + (size_t)bh * S_ * DH_;
    const u16* Kg = (const u16*)Kh + (size_t)bh * S_ * DH_;
    const u16* Vg = (const u16*)Vt + (size_t)bh * DH_ * S_;

    // Q fragments straight from global (B-operand: n=q=ln, k=d=32ks+8quad+j)
    half8 qf[2];
    #pragma unroll
    for (int ks = 0; ks < 2; ++ks)
        qf[ks] = __builtin_bit_cast(half8,
            *(const uint4*)(Qg + (size_t)(qbase + ln) * DH_ + 32 * ks + 8 * quad));

    // staging coords: K rows kr+32j (j=0..3); V e-rows kr,kr+32 x col-halves
    const int kr = tid >> 3;           // 0..31
    const int kc = (tid & 7) * 8;      // 0..56

    // prefetch tile 0 (t in [0,128); 64 <= vmax always since vmax >= 1055)
    uint4 ka = *(const uint4*)(Kg + (size_t)(kr)      * DH_ + kc);
    uint4 kb = *(const uint4*)(Kg + (size_t)(kr + 32) * DH_ + kc);
    uint4 kcg= *(const uint4*)(Kg + (size_t)(kr + 64) * DH_ + kc);
    uint4 kd = *(const uint4*)(Kg + (size_t)(kr + 96) * DH_ + kc);
    uint4 va = *(const uint4*)(Vg + (size_t)(kr)      * S_ + kc);
    uint4 vb = *(const uint4*)(Vg + (size_t)(kr + 32) * S_ + kc);
    uint4 vc = *(const uint4*)(Vg + (size_t)(kr)      * S_ + 64 + kc);
    uint4 vd = *(const uint4*)(Vg + (size_t)(kr + 32) * S_ + 64 + kc);

    float l_r = 0.f;
    f32x4 o_acc[4];
    #pragma unroll
    for (int nt = 0; nt < 4; ++nt) o_acc[nt] = (f32x4){0.f, 0.f, 0.f, 0.f};

    const int qrow   = qbase + ln;     // this lane's q (n-dim)
    const int pv_lim = qbase + 15;     // wave-uniform PV bound

    for (int t0 = 0; t0 < S_; t0 += 128){
        __syncthreads();               // all waves done reading prev tile
        *(uint4*)&Ks[(kr)      * AKS + kc] = ka;
        *(uint4*)&Ks[(kr + 32) * AKS + kc] = kb;
        *(uint4*)&Ks[(kr + 64) * AKS + kc] = kcg;
        *(uint4*)&Ks[(kr + 96) * AKS + kc] = kd;
        if (t0 <= vmax){
            *(uint4*)&Vs[(kr)      * VKS + kc] = va;
            *(uint4*)&Vs[(kr + 32) * VKS + kc] = vb;
        }
        if (t0 + 64 <= vmax){
            *(uint4*)&Vs[(kr)      * VKS + 64 + kc] = vc;
            *(uint4*)&Vs[(kr + 32) * VKS + 64 + kc] = vd;
        }
        // prefetch tile t0+128 (hidden behind this tile's 2x compute)
        const int tp = t0 + 128;
        if (tp < S_){
            ka = *(const uint4*)(Kg + (size_t)(tp + kr)      * DH_ + kc);
            kb = *(const uint4*)(Kg + (size_t)(tp + kr + 32) * DH_ + kc);
            kcg= *(const uint4*)(Kg + (size_t)(tp + kr + 64) * DH_ + kc);
            kd = *(const uint4*)(Kg + (size_t)(tp + kr + 96) * DH_ + kc);
            if (tp <= vmax){
                va = *(const uint4*)(Vg + (size_t)(kr)      * S_ + tp + kc);
                vb = *(const uint4*)(Vg + (size_t)(kr + 32) * S_ + tp + kc);
            }
            if (tp + 64 <= vmax){
                vc = *(const uint4*)(Vg + (size_t)(kr)      * S_ + tp + 64 + kc);
                vd = *(const uint4*)(Vg + (size_t)(kr + 32) * S_ + tp + 64 + kc);
            }
        }
        __syncthreads();               // LDS tile ready

        // two 64-t sub-tiles, identical t-order to R0's successive iters
        #pragma unroll
        for (int si = 0; si < 2; ++si){
            const int tb   = t0 + 64 * si;
            const int koff = 64 * si * AKS;
            const int voff = 64 * si;

            f32x4 sc[4];
            #pragma unroll
            for (int mt = 0; mt < 4; ++mt) sc[mt] = (f32x4){0.f, 0.f, 0.f, 0.f};
            #pragma unroll
            for (int ks = 0; ks < 2; ++ks)
                #pragma unroll
                for (int mt = 0; mt < 4; ++mt){
                    half8 kf = __builtin_bit_cast(half8,
                        *(const uint4*)&Ks[koff + (16 * mt + ln) * AKS + 32 * ks + 8 * quad]);
                    sc[mt] = __builtin_amdgcn_mfma_f32_16x16x32_f16(kf, qf[ks], sc[mt], 0, 0, 0);
                }

            // p = exp2(s); denominator = plain running row-sum over ALL t
            #pragma unroll
            for (int mt = 0; mt < 4; ++mt)
                #pragma unroll
                for (int r = 0; r < 4; ++r)
                    sc[mt][r] = EXP2(sc[mt][r]);
            float s = ((sc[0][0] + sc[0][1] + sc[0][2] + sc[0][3]) +
                       (sc[1][0] + sc[1][1] + sc[1][2] + sc[1][3])) +
                      ((sc[2][0] + sc[2][1] + sc[2][2] + sc[2][3]) +
                       (sc[3][0] + sc[3][1] + sc[3][2] + sc[3][3]));
            s += __shfl_xor(s, 16);
            s += __shfl_xor(s, 32);
            l_r += s;

            // PV per 16-t subtile; only the subtile starting AT qbase partial
            #pragma unroll
            for (int mt = 0; mt < 4; ++mt){
                const int ts = tb + 16 * mt;
                if (ts <= pv_lim){         // wave-uniform
                    half4 pf;
                    if (ts == qbase){      // the one partial subtile
                        int tq = ts + 4 * quad;
                        #pragma unroll
                        for (int r = 0; r < 4; ++r)
                            pf[r] = (tq + r > qrow) ? (f16)0.f : (f16)sc[mt][r];
                    } else {               // fully below diagonal
                        #pragma unroll
                        for (int r = 0; r < 4; ++r)
                            pf[r] = (f16)sc[mt][r];
                    }
                    #pragma unroll
                    for (int nt = 0; nt < 4; ++nt){
                        half4 vf = __builtin_bit_cast(half4,
                            *(const uint2*)&Vs[(16 * nt + ln) * VKS + voff + 16 * mt + 4 * quad]);
                        o_acc[nt] = __builtin_amdgcn_mfma_f32_16x16x16f16(pf, vf, o_acc[nt], 0, 0, 0);
                    }
                }
            }
        }
    }

    // epilogue: o rows at q = qbase+4quad+r; l lives at lane ln=row
    #pragma unroll
    for (int r = 0; r < 4; ++r){
        float lv  = __shfl(l_r, (lane & 48) | (4 * quad + r));
        float inv = 1.0f / lv;
        int sg = qbase + 4 * quad + r;
        float* op = Out + ((size_t)b * S_ + sg) * D_ + h * DH_;
        #pragma unroll
        for (int nt = 0; nt < 4; ++nt)
            op[16 * nt + ln] = o_acc[nt][r] * inv;
    }
}

// ---------------------------------------------------------------------------
extern "C" void kernel_launch(void* const* d_in, const int* in_sizes, int n_in,
                              void* d_out, int out_size, void* d_ws, size_t ws_size,
                              hipStream_t stream)
{
    const float* X  = (const float*)d_in[0];
    const float* Wq = (const float*)d_in[1];
    const float* bq = (const float*)d_in[2];
    const float* Wk = (const float*)d_in[3];
    const float* bk = (const float*)d_in[4];
    const float* Wv = (const float*)d_in[5];
    const float* bv = (const float*)d_in[6];
    float* out = (float*)d_out;

    // workspace (~31.5 MiB): Wt | Qh | Kh | Vt
    u16* Wt  = (u16*)d_ws;                    // 3,145,728 u16
    f16* Qh  = (f16*)(Wt + 3145728);
    f16* Kh  = Qh + 4194304;
    f16* Vt  = Kh + 4194304;

    prep_kernel<<<dim3(768), 256, 0, stream>>>(Wq, Wk, Wv, Wt);
    proj_kernel<<<dim3(32, 24), 256, 0, stream>>>(X, Wt, bq, bk, bv, Qh, Kh, Vt);
    attn_kernel<<<dim3(32, 32), 256, 0, stream>>>(Qh, Kh, Vt, out);
}